// Round 5
// baseline (2943.709 us; speedup 1.0000x reference)
//
#include <hip/hip_runtime.h>

#define NB 1024   // boxes
#define NC 151    // classes
#define NCP 152   // padded probs row stride (16B-aligned)
#define DF 4096   // feature dim
typedef unsigned long long u64;

// ---------------- GEMM: dists = fmap @ W + b (fp32 in, f64 accum) ----------------
__global__ __launch_bounds__(192) void gemm_kernel(
    const float* __restrict__ fmap, const float* __restrict__ W,
    const float* __restrict__ bias, float* __restrict__ dists) {
  __shared__ float sf[4 * DF];  // 64 KiB
  int r0 = blockIdx.x * 4;
  const float4* src = (const float4*)(fmap + (size_t)r0 * DF);
  for (int i = threadIdx.x; i < 4 * (DF / 4); i += 192) {
    int r = i >> 10;       // row 0..3
    int q = i & 1023;      // float4 index within row
    float4 v = src[i];
    sf[(4 * q + 0) * 4 + r] = v.x;
    sf[(4 * q + 1) * 4 + r] = v.y;
    sf[(4 * q + 2) * 4 + r] = v.z;
    sf[(4 * q + 3) * 4 + r] = v.w;
  }
  __syncthreads();
  int c = threadIdx.x;
  if (c < NC) {
    double a0 = 0.0, a1 = 0.0, a2 = 0.0, a3 = 0.0;
    const float* w = W + c;
    const float4* sf4 = (const float4*)sf;
#pragma unroll 8
    for (int d = 0; d < DF; ++d) {
      float4 f = sf4[d];                       // broadcast across wave
      double wv = (double)w[(size_t)d * NC];   // coalesced across threads
      a0 += (double)f.x * wv;
      a1 += (double)f.y * wv;
      a2 += (double)f.z * wv;
      a3 += (double)f.w * wv;
    }
    float b = bias[c];
    dists[(size_t)(r0 + 0) * NC + c] = (float)a0 + b;
    dists[(size_t)(r0 + 1) * NC + c] = (float)a1 + b;
    dists[(size_t)(r0 + 2) * NC + c] = (float)a2 + b;
    dists[(size_t)(r0 + 3) * NC + c] = (float)a3 + b;
  }
}

// ---------------- softmax rows into padded probs, zero background col ----------------
__global__ __launch_bounds__(64) void softmax_kernel(
    const float* __restrict__ dists, float* __restrict__ probs) {
  int row = blockIdx.x;
  int t = threadIdx.x;
  const float* x = dists + (size_t)row * NC;
  float v0 = x[t];
  float v1 = x[t + 64];
  float v2 = (t + 128 < NC) ? x[t + 128] : -3.0e38f;
  float m = fmaxf(fmaxf(v0, v1), v2);
  for (int off = 32; off; off >>= 1) m = fmaxf(m, __shfl_down(m, off));
  m = __shfl(m, 0);
  float e0 = expf(v0 - m), e1 = expf(v1 - m);
  float e2 = (t + 128 < NC) ? expf(v2 - m) : 0.0f;
  float s = e0 + e1 + e2;
  for (int off = 32; off; off >>= 1) s += __shfl_down(s, off);
  s = __shfl(s, 0);
  float* p = probs + (size_t)row * NCP;
  p[t] = (t == 0) ? 0.0f : (e0 / s);
  p[t + 64] = e1 / s;
  if (t + 128 < NC) p[t + 128] = e2 / s;
  if (t == 0) p[NC] = -1.0f;  // pad col never wins a scan
}

// ---------------- transpose boxes to [C][N][4] ----------------
__global__ __launch_bounds__(256) void transpose_kernel(
    const float* __restrict__ boxes, float* __restrict__ boxes_t) {
  int idx = blockIdx.x * 256 + threadIdx.x;  // idx = c*NB + n
  if (idx >= NC * NB) return;
  int c = idx >> 10;
  int n = idx & (NB - 1);
  float4 b = *(const float4*)(boxes + ((size_t)n * NC + c) * 4);
  *(float4*)(boxes_t + (size_t)idx * 4) = b;
}

// ---------------- precompute overlap bitmask: mask[cl][b] = 1024 bits ----------------
__global__ __launch_bounds__(256) void mask_kernel(
    const float* __restrict__ boxes_t, u64* __restrict__ mask) {
#pragma clang fp contract(off)
  int cl = blockIdx.x >> 4;          // 151 classes
  int bb = (blockIdx.x & 15) * 64;   // 16 b-groups of 64
  __shared__ float4 sbox[NB];
  __shared__ float sarea[NB];
  const float4* col = (const float4*)(boxes_t + (size_t)cl * NB * 4);
  for (int i = threadIdx.x; i < NB; i += 256) {
    float4 b = col[i];
    sbox[i] = b;
    sarea[i] = (b.z - b.x + 1.0f) * (b.w - b.y + 1.0f);
  }
  __syncthreads();
  int wv = threadIdx.x >> 6, lane = threadIdx.x & 63;
  for (int j = 0; j < 16; ++j) {
    int b = bb + wv * 16 + j;
    float4 B = sbox[b];
    float areaB = sarea[b];
    u64 myword = 0;
#pragma unroll
    for (int k = 0; k < 16; ++k) {
      int r = k * 64 + lane;
      float4 R = sbox[r];
      float ix = fminf(B.z, R.z) - fmaxf(B.x, R.x) + 1.0f;
      float iy = fminf(B.w, R.w) - fmaxf(B.y, R.y) + 1.0f;
      ix = fmaxf(ix, 0.0f);
      iy = fmaxf(iy, 0.0f);
      float inter = ix * iy;
      float uni = sarea[r] + areaB - inter;
      float iou = inter / uni;            // IEEE div — must match numpy exactly
      u64 bal = __ballot(iou >= 0.5f);
      if (lane == k) myword = bal;
    }
    if (lane < 16) mask[((size_t)cl * NB + b) * 16 + lane] = myword;
  }
}

// ---------------- greedy commit: ONE wave, register-only state, prefetch ----------------
template <int CTRL, int ROWMASK>
__device__ __forceinline__ float dpp_max_step(float v) {
  int x = __float_as_int(v);
  int t = __builtin_amdgcn_update_dpp(x, x, CTRL, ROWMASK, 0xf, false);
  return fmaxf(v, __int_as_float(t));
}

// canonical gfx9 wave64 max reduce; result broadcast via readlane(63)
__device__ __forceinline__ float wave_max(float v) {
  v = dpp_max_step<0x111, 0xf>(v);  // row_shr:1
  v = dpp_max_step<0x112, 0xf>(v);  // row_shr:2
  v = dpp_max_step<0x114, 0xf>(v);  // row_shr:4
  v = dpp_max_step<0x118, 0xf>(v);  // row_shr:8
  v = dpp_max_step<0x142, 0xa>(v);  // row_bcast:15
  v = dpp_max_step<0x143, 0xc>(v);  // row_bcast:31
  return __int_as_float(__builtin_amdgcn_readlane(__float_as_int(v), 63));
}

// argmax over the lane's 16 rows, tree-structured; ties -> smaller row.
// excl (runtime, or -1): treat that row as -2 (for runner-up prediction).
__device__ __forceinline__ void local_argmax(const float rm[16], const int ra[16],
                                             int excl, float& v_out, int& p_out) {
  float tv[8]; int tp[8];
#pragma unroll
  for (int i = 0; i < 8; ++i) {
    int r0 = 2 * i, r1 = 2 * i + 1;
    float a = (r0 == excl) ? -2.0f : rm[r0];
    float b = (r1 == excl) ? -2.0f : rm[r1];
    int pa = (r0 << 8) | ra[r0];
    int pb = (r1 << 8) | ra[r1];
    bool t = b > a;
    tv[i] = t ? b : a; tp[i] = t ? pb : pa;
  }
#pragma unroll
  for (int i = 0; i < 4; ++i) {
    bool t = tv[2 * i + 1] > tv[2 * i];
    tv[i] = t ? tv[2 * i + 1] : tv[2 * i];
    tp[i] = t ? tp[2 * i + 1] : tp[2 * i];
  }
#pragma unroll
  for (int i = 0; i < 2; ++i) {
    bool t = tv[2 * i + 1] > tv[2 * i];
    tv[i] = t ? tv[2 * i + 1] : tv[2 * i];
    tp[i] = t ? tp[2 * i + 1] : tp[2 * i];
  }
  bool t = tv[1] > tv[0];
  v_out = t ? tv[1] : tv[0];
  p_out = t ? tp[1] : tp[0];
}

// scan a read-only probs row with zeroed-class bitmask applied; strict >, first max.
__device__ __noinline__ void rescan_row(const float* __restrict__ pp,
                                        u64 z0, u64 z1, u64 z2,
                                        float* __restrict__ mo, int* __restrict__ ao) {
  const float4* p4 = (const float4*)pp;
  float m = 0.0f; int a = 0;
  for (int q = 0; q < NCP / 4; ++q) {
    float4 v = p4[q];
    u64 z = q < 16 ? z0 : (q < 32 ? z1 : z2);
    unsigned bits = (unsigned)(z >> ((q & 15) * 4)) & 0xFu;
    int c0 = q * 4;
    float vx = (bits & 1u) ? 0.0f : v.x;
    float vy = (bits & 2u) ? 0.0f : v.y;
    float vz = (bits & 4u) ? 0.0f : v.z;
    float vw = (bits & 8u) ? 0.0f : v.w;
    if (vx > m) { m = vx; a = c0; }
    if (vy > m) { m = vy; a = c0 + 1; }
    if (vz > m) { m = vz; a = c0 + 2; }
    if (vw > m) { m = vw; a = c0 + 3; }
  }
  *mo = m; *ao = a;
}

__global__ __launch_bounds__(64) void greedy_kernel(
    const float* __restrict__ probs, const u64* __restrict__ mask,
    float* __restrict__ out_preds) {
  int lane = threadIdx.x;
  float rm[16];
  int ra[16];
  int cm[16];
  u64 zb0[16], zb1[16], zb2[16];  // zeroed-class bits: word cl>>6, bit cl&63
  unsigned committed = 0;

  // ---- init: scan my 16 rows (no zeroed classes yet) ----
#pragma unroll
  for (int r = 0; r < 16; ++r) {
    rescan_row(probs + (size_t)((lane << 4) | r) * NCP, 0, 0, 0, &rm[r], &ra[r]);
    cm[r] = 0; zb0[r] = 0; zb1[r] = 0; zb2[r] = 0;
  }

  int pf_b = -1, pf_cl = -1;
  u64 pf_word = 0;

  for (int it = 0; it < NB; ++it) {
    // ---- winner selection ----
    float bv; int bp;
    local_argmax(rm, ra, -1, bv, bp);
    float wmax = wave_max(bv);
    u64 ball = __ballot(bv == wmax);
    int winner = __ffsll(ball) - 1;         // smallest lane = smallest row
    int pw = __builtin_amdgcn_readlane(bp, winner);
    int b = (winner << 4) | (pw >> 8);
    int cl = pw & 0xff;

    // ---- mask word: prefetch hit (wave-uniform) or fresh load ----
    u64 word;
    if (b == pf_b && cl == pf_cl) {
      word = pf_word;
    } else {
      word = mask[(((size_t)cl << 10) | (size_t)b) * 16 + (lane >> 2)];
    }

    // ---- runner-up prediction (VALU-only, overlaps mask wait) + prefetch ----
    {
      int excl = (lane == winner) ? (pw >> 8) : -1;
      float bv2; int bp2;
      local_argmax(rm, ra, excl, bv2, bp2);
      float wmax2 = wave_max(bv2);
      u64 ball2 = __ballot(bv2 == wmax2);
      int w2 = __ffsll(ball2) - 1;
      int pw2 = __builtin_amdgcn_readlane(bp2, w2);
      pf_b = (w2 << 4) | (pw2 >> 8);
      pf_cl = pw2 & 0xff;
      pf_word = mask[(((size_t)pf_cl << 10) | (size_t)pf_b) * 16 + (lane >> 2)];
    }

    unsigned hits = (unsigned)(word >> ((lane & 3) << 4)) & 0xFFFFu;

    // per-word bit of class cl (wave-uniform), branch-free
    int wi = cl >> 6;
    u64 bm = 1ull << (cl & 63);
    u64 m0 = (wi == 0) ? bm : 0, m1 = (wi == 1) ? bm : 0, m2 = (wi == 2) ? bm : 0;

    // ---- update my rows ----
    unsigned need = 0;
#pragma unroll
    for (int r = 0; r < 16; ++r) {
      int grow = (lane << 4) | r;
      unsigned rb = 1u << r;
      if (grow == b) {
        committed |= rb;
        rm[r] = -1.0f;       // row becomes all -1 (wipes prior re-zeros)
        cm[r] = cl;          // commit (or re-commit)
      } else if (hits & rb) {
        if (committed & rb) {
          // committed row: -1 everywhere except re-zeroed cols (0)
          if (rm[r] < 0.0f) { rm[r] = 0.0f; ra[r] = cl; }
          else if (cl < ra[r]) ra[r] = cl;
        } else {
          zb0[r] |= m0; zb1[r] |= m1; zb2[r] |= m2;
          if (ra[r] == cl) need |= rb;  // max may have dropped
        }
      }
    }
    if (__ballot(need != 0)) {  // uniform skip when no lane rescans
#pragma unroll
      for (int r = 0; r < 16; ++r) {
        if (need & (1u << r))
          rescan_row(probs + (size_t)((lane << 4) | r) * NCP,
                     zb0[r], zb1[r], zb2[r], &rm[r], &ra[r]);
      }
    }
  }

  // ---- write commits ----
#pragma unroll
  for (int r = 0; r < 16; ++r)
    out_preds[(lane << 4) | r] = (float)cm[r];
}

// ---------------- host ----------------
extern "C" void kernel_launch(void* const* d_in, const int* in_sizes, int n_in,
                              void* d_out, int out_size, void* d_ws, size_t ws_size,
                              hipStream_t stream) {
  const float* obj_fmap = (const float*)d_in[0];  // [NB, DF]
  const float* W_out    = (const float*)d_in[1];  // [DF, NC]
  const float* b_out    = (const float*)d_in[2];  // [NC]
  const float* boxes    = (const float*)d_in[3];  // [NB, NC, 4]

  float* out_dists = (float*)d_out;            // NB*NC
  float* out_preds = (float*)d_out + NB * NC;  // NB (as float)

  float* probs   = (float*)d_ws;                        // NB*NCP floats
  float* boxes_t = probs + (size_t)NB * NCP;            // NC*NB*4 floats
  u64*   mask    = (u64*)(boxes_t + (size_t)NC * NB * 4);  // NC*NB*16 u64 (19.8 MB)

  gemm_kernel<<<NB / 4, 192, 0, stream>>>(obj_fmap, W_out, b_out, out_dists);
  softmax_kernel<<<NB, 64, 0, stream>>>(out_dists, probs);
  transpose_kernel<<<(NC * NB + 255) / 256, 256, 0, stream>>>(boxes, boxes_t);
  mask_kernel<<<NC * 16, 256, 0, stream>>>(boxes_t, mask);
  greedy_kernel<<<1, 64, 0, stream>>>(probs, mask, out_preds);
}

// Round 6
// 2225.716 us; speedup vs baseline: 1.3226x; 1.3226x over previous
//
#include <hip/hip_runtime.h>

#define NB 1024   // boxes
#define NC 151    // classes
#define NCP 152   // padded probs row stride (16B-aligned)
#define DF 4096   // feature dim
typedef unsigned long long u64;

// ---------------- GEMM: dists = fmap @ W + b (fp32 in, f64 accum) ----------------
__global__ __launch_bounds__(192) void gemm_kernel(
    const float* __restrict__ fmap, const float* __restrict__ W,
    const float* __restrict__ bias, float* __restrict__ dists) {
  __shared__ float sf[4 * DF];  // 64 KiB
  int r0 = blockIdx.x * 4;
  const float4* src = (const float4*)(fmap + (size_t)r0 * DF);
  for (int i = threadIdx.x; i < 4 * (DF / 4); i += 192) {
    int r = i >> 10;       // row 0..3
    int q = i & 1023;      // float4 index within row
    float4 v = src[i];
    sf[(4 * q + 0) * 4 + r] = v.x;
    sf[(4 * q + 1) * 4 + r] = v.y;
    sf[(4 * q + 2) * 4 + r] = v.z;
    sf[(4 * q + 3) * 4 + r] = v.w;
  }
  __syncthreads();
  int c = threadIdx.x;
  if (c < NC) {
    double a0 = 0.0, a1 = 0.0, a2 = 0.0, a3 = 0.0;
    const float* w = W + c;
    const float4* sf4 = (const float4*)sf;
#pragma unroll 8
    for (int d = 0; d < DF; ++d) {
      float4 f = sf4[d];                       // broadcast across wave
      double wv = (double)w[(size_t)d * NC];   // coalesced across threads
      a0 += (double)f.x * wv;
      a1 += (double)f.y * wv;
      a2 += (double)f.z * wv;
      a3 += (double)f.w * wv;
    }
    float b = bias[c];
    dists[(size_t)(r0 + 0) * NC + c] = (float)a0 + b;
    dists[(size_t)(r0 + 1) * NC + c] = (float)a1 + b;
    dists[(size_t)(r0 + 2) * NC + c] = (float)a2 + b;
    dists[(size_t)(r0 + 3) * NC + c] = (float)a3 + b;
  }
}

// ---------------- softmax rows into padded probs, zero background col ----------------
__global__ __launch_bounds__(64) void softmax_kernel(
    const float* __restrict__ dists, float* __restrict__ probs) {
  int row = blockIdx.x;
  int t = threadIdx.x;
  const float* x = dists + (size_t)row * NC;
  float v0 = x[t];
  float v1 = x[t + 64];
  float v2 = (t + 128 < NC) ? x[t + 128] : -3.0e38f;
  float m = fmaxf(fmaxf(v0, v1), v2);
  for (int off = 32; off; off >>= 1) m = fmaxf(m, __shfl_down(m, off));
  m = __shfl(m, 0);
  float e0 = expf(v0 - m), e1 = expf(v1 - m);
  float e2 = (t + 128 < NC) ? expf(v2 - m) : 0.0f;
  float s = e0 + e1 + e2;
  for (int off = 32; off; off >>= 1) s += __shfl_down(s, off);
  s = __shfl(s, 0);
  float* p = probs + (size_t)row * NCP;
  p[t] = (t == 0) ? 0.0f : (e0 / s);
  p[t + 64] = e1 / s;
  if (t + 128 < NC) p[t + 128] = e2 / s;
  if (t == 0) p[NC] = -1.0f;  // pad col never wins a scan
}

// ---------------- transpose boxes to [C][N][4] ----------------
__global__ __launch_bounds__(256) void transpose_kernel(
    const float* __restrict__ boxes, float* __restrict__ boxes_t) {
  int idx = blockIdx.x * 256 + threadIdx.x;  // idx = c*NB + n
  if (idx >= NC * NB) return;
  int c = idx >> 10;
  int n = idx & (NB - 1);
  float4 b = *(const float4*)(boxes + ((size_t)n * NC + c) * 4);
  *(float4*)(boxes_t + (size_t)idx * 4) = b;
}

// ---------------- precompute overlap bitmask: mask[cl][b] = 1024 bits ----------------
__global__ __launch_bounds__(256) void mask_kernel(
    const float* __restrict__ boxes_t, u64* __restrict__ mask) {
#pragma clang fp contract(off)
  int cl = blockIdx.x >> 4;          // 151 classes
  int bb = (blockIdx.x & 15) * 64;   // 16 b-groups of 64
  __shared__ float4 sbox[NB];
  __shared__ float sarea[NB];
  const float4* col = (const float4*)(boxes_t + (size_t)cl * NB * 4);
  for (int i = threadIdx.x; i < NB; i += 256) {
    float4 b = col[i];
    sbox[i] = b;
    sarea[i] = (b.z - b.x + 1.0f) * (b.w - b.y + 1.0f);
  }
  __syncthreads();
  int wv = threadIdx.x >> 6, lane = threadIdx.x & 63;
  for (int j = 0; j < 16; ++j) {
    int b = bb + wv * 16 + j;
    float4 B = sbox[b];
    float areaB = sarea[b];
    u64 myword = 0;
#pragma unroll
    for (int k = 0; k < 16; ++k) {
      int r = k * 64 + lane;
      float4 R = sbox[r];
      float ix = fminf(B.z, R.z) - fmaxf(B.x, R.x) + 1.0f;
      float iy = fminf(B.w, R.w) - fmaxf(B.y, R.y) + 1.0f;
      ix = fmaxf(ix, 0.0f);
      iy = fmaxf(iy, 0.0f);
      float inter = ix * iy;
      float uni = sarea[r] + areaB - inter;
      float iou = inter / uni;            // IEEE div — must match numpy exactly
      u64 bal = __ballot(iou >= 0.5f);
      if (lane == k) myword = bal;
    }
    if (lane < 16) mask[((size_t)cl * NB + b) * 16 + lane] = myword;
  }
}

// ---------------- greedy commit: ONE wave, register-only state, no calls ----------------
template <int CTRL, int ROWMASK>
__device__ __forceinline__ float dpp_max_step(float v) {
  int x = __float_as_int(v);
  int t = __builtin_amdgcn_update_dpp(x, x, CTRL, ROWMASK, 0xf, false);
  return fmaxf(v, __int_as_float(t));
}

// canonical gfx9 wave64 max reduce; result broadcast via readlane(63)
__device__ __forceinline__ float wave_max(float v) {
  v = dpp_max_step<0x111, 0xf>(v);  // row_shr:1
  v = dpp_max_step<0x112, 0xf>(v);  // row_shr:2
  v = dpp_max_step<0x114, 0xf>(v);  // row_shr:4
  v = dpp_max_step<0x118, 0xf>(v);  // row_shr:8
  v = dpp_max_step<0x142, 0xa>(v);  // row_bcast:15
  v = dpp_max_step<0x143, 0xc>(v);  // row_bcast:31
  return __int_as_float(__builtin_amdgcn_readlane(__float_as_int(v), 63));
}

// scan a read-only probs row with zeroed-class bitmask applied; strict >, first max.
__device__ __forceinline__ void rescan_row(const float* __restrict__ pp,
                                           u64 z0, u64 z1, u64 z2,
                                           float& mo, int& ao) {
  const float4* p4 = (const float4*)pp;
  float m = 0.0f; int a = 0;
#pragma unroll 2
  for (int q = 0; q < NCP / 4; ++q) {
    float4 v = p4[q];
    u64 z = q < 16 ? z0 : (q < 32 ? z1 : z2);
    unsigned bits = (unsigned)(z >> ((q & 15) * 4)) & 0xFu;
    int c0 = q * 4;
    float vx = (bits & 1u) ? 0.0f : v.x;
    float vy = (bits & 2u) ? 0.0f : v.y;
    float vz = (bits & 4u) ? 0.0f : v.z;
    float vw = (bits & 8u) ? 0.0f : v.w;
    if (vx > m) { m = vx; a = c0; }
    if (vy > m) { m = vy; a = c0 + 1; }
    if (vz > m) { m = vz; a = c0 + 2; }
    if (vw > m) { m = vw; a = c0 + 3; }
  }
  mo = m; ao = a;
}

__global__ __launch_bounds__(64) void greedy_kernel(
    const float* __restrict__ probs, const u64* __restrict__ mask,
    float* __restrict__ out_preds) {
  int lane = threadIdx.x;
  float rm[16];
  int ra[16];
  int cm[16];
  u64 zb0[16], zb1[16], zb2[16];  // zeroed-class bits: word cl>>6, bit cl&63
  unsigned committed = 0;

  // ---- init: scan my 16 rows (no zeroed classes yet) ----
#pragma unroll
  for (int r = 0; r < 16; ++r) {
    rescan_row(probs + (size_t)((lane << 4) | r) * NCP, 0, 0, 0, rm[r], ra[r]);
    cm[r] = 0; zb0[r] = 0; zb1[r] = 0; zb2[r] = 0;
  }

  for (int it = 0; it < NB; ++it) {
    // ---- local argmax over my 16 rows (strict > ascending => smallest row on tie) ----
    float bv = rm[0];
    int bp = ra[0];  // packed (r<<8)|ra
#pragma unroll
    for (int r = 1; r < 16; ++r) {
      int p = (r << 8) | ra[r];
      bool t = rm[r] > bv;
      bv = t ? rm[r] : bv;
      bp = t ? p : bp;
    }

    // ---- wave winner ----
    float wmax = wave_max(bv);
    u64 ball = __ballot(bv == wmax);
    int winner = __ffsll(ball) - 1;        // smallest lane = smallest row
    int pw = __builtin_amdgcn_readlane(bp, winner);
    int b = (winner << 4) | (pw >> 8);
    int cl = pw & 0xff;

    // ---- one coalesced 128B mask-column load (issued ASAP) ----
    u64 word = mask[(((size_t)cl << 10) | (size_t)b) * 16 + (lane >> 2)];

    // per-word bit of class cl (wave-uniform), branch-free — overlaps load wait
    int wi = cl >> 6;
    u64 bm = 1ull << (cl & 63);
    u64 m0 = (wi == 0) ? bm : 0, m1 = (wi == 1) ? bm : 0, m2 = (wi == 2) ? bm : 0;

    unsigned hits = (unsigned)(word >> ((lane & 3) << 4)) & 0xFFFFu;

    // ---- update my rows ----
    unsigned need = 0;
#pragma unroll
    for (int r = 0; r < 16; ++r) {
      int grow = (lane << 4) | r;
      unsigned rb = 1u << r;
      if (grow == b) {
        committed |= rb;
        rm[r] = -1.0f;       // row becomes all -1 (wipes prior re-zeros)
        cm[r] = cl;          // commit (or re-commit)
      } else if (hits & rb) {
        if (committed & rb) {
          // committed row: -1 everywhere except re-zeroed cols (0)
          if (rm[r] < 0.0f) { rm[r] = 0.0f; ra[r] = cl; }
          else if (cl < ra[r]) ra[r] = cl;
        } else {
          zb0[r] |= m0; zb1[r] |= m1; zb2[r] |= m2;
          if (ra[r] == cl) need |= rb;  // max may have dropped
        }
      }
    }
    if (__ballot(need != 0)) {  // uniform skip when no lane rescans
#pragma unroll
      for (int r = 0; r < 16; ++r) {
        if (need & (1u << r))
          rescan_row(probs + (size_t)((lane << 4) | r) * NCP,
                     zb0[r], zb1[r], zb2[r], rm[r], ra[r]);
      }
    }
  }

  // ---- write commits ----
#pragma unroll
  for (int r = 0; r < 16; ++r)
    out_preds[(lane << 4) | r] = (float)cm[r];
}

// ---------------- host ----------------
extern "C" void kernel_launch(void* const* d_in, const int* in_sizes, int n_in,
                              void* d_out, int out_size, void* d_ws, size_t ws_size,
                              hipStream_t stream) {
  const float* obj_fmap = (const float*)d_in[0];  // [NB, DF]
  const float* W_out    = (const float*)d_in[1];  // [DF, NC]
  const float* b_out    = (const float*)d_in[2];  // [NC]
  const float* boxes    = (const float*)d_in[3];  // [NB, NC, 4]

  float* out_dists = (float*)d_out;            // NB*NC
  float* out_preds = (float*)d_out + NB * NC;  // NB (as float)

  float* probs   = (float*)d_ws;                        // NB*NCP floats
  float* boxes_t = probs + (size_t)NB * NCP;            // NC*NB*4 floats
  u64*   mask    = (u64*)(boxes_t + (size_t)NC * NB * 4);  // NC*NB*16 u64 (19.8 MB)

  gemm_kernel<<<NB / 4, 192, 0, stream>>>(obj_fmap, W_out, b_out, out_dists);
  softmax_kernel<<<NB, 64, 0, stream>>>(out_dists, probs);
  transpose_kernel<<<(NC * NB + 255) / 256, 256, 0, stream>>>(boxes, boxes_t);
  mask_kernel<<<NC * 16, 256, 0, stream>>>(boxes_t, mask);
  greedy_kernel<<<1, 64, 0, stream>>>(probs, mask, out_preds);
}

// Round 7
// 2214.922 us; speedup vs baseline: 1.3290x; 1.0049x over previous
//
#include <hip/hip_runtime.h>

#define NB 1024   // boxes
#define NC 151    // classes
#define NCP 152   // padded probs row stride (16B-aligned)
#define DF 4096   // feature dim
typedef unsigned long long u64;

// ---------------- GEMM: dists = fmap @ W + b (fp32 in, f64 accum) ----------------
__global__ __launch_bounds__(192) void gemm_kernel(
    const float* __restrict__ fmap, const float* __restrict__ W,
    const float* __restrict__ bias, float* __restrict__ dists) {
  __shared__ float sf[4 * DF];  // 64 KiB
  int r0 = blockIdx.x * 4;
  const float4* src = (const float4*)(fmap + (size_t)r0 * DF);
  for (int i = threadIdx.x; i < 4 * (DF / 4); i += 192) {
    int r = i >> 10;       // row 0..3
    int q = i & 1023;      // float4 index within row
    float4 v = src[i];
    sf[(4 * q + 0) * 4 + r] = v.x;
    sf[(4 * q + 1) * 4 + r] = v.y;
    sf[(4 * q + 2) * 4 + r] = v.z;
    sf[(4 * q + 3) * 4 + r] = v.w;
  }
  __syncthreads();
  int c = threadIdx.x;
  if (c < NC) {
    double a0 = 0.0, a1 = 0.0, a2 = 0.0, a3 = 0.0;
    const float* w = W + c;
    const float4* sf4 = (const float4*)sf;
#pragma unroll 8
    for (int d = 0; d < DF; ++d) {
      float4 f = sf4[d];                       // broadcast across wave
      double wv = (double)w[(size_t)d * NC];   // coalesced across threads
      a0 += (double)f.x * wv;
      a1 += (double)f.y * wv;
      a2 += (double)f.z * wv;
      a3 += (double)f.w * wv;
    }
    float b = bias[c];
    dists[(size_t)(r0 + 0) * NC + c] = (float)a0 + b;
    dists[(size_t)(r0 + 1) * NC + c] = (float)a1 + b;
    dists[(size_t)(r0 + 2) * NC + c] = (float)a2 + b;
    dists[(size_t)(r0 + 3) * NC + c] = (float)a3 + b;
  }
}

// ---------------- softmax rows into padded probs, zero background col ----------------
__global__ __launch_bounds__(64) void softmax_kernel(
    const float* __restrict__ dists, float* __restrict__ probs) {
  int row = blockIdx.x;
  int t = threadIdx.x;
  const float* x = dists + (size_t)row * NC;
  float v0 = x[t];
  float v1 = x[t + 64];
  float v2 = (t + 128 < NC) ? x[t + 128] : -3.0e38f;
  float m = fmaxf(fmaxf(v0, v1), v2);
  for (int off = 32; off; off >>= 1) m = fmaxf(m, __shfl_down(m, off));
  m = __shfl(m, 0);
  float e0 = expf(v0 - m), e1 = expf(v1 - m);
  float e2 = (t + 128 < NC) ? expf(v2 - m) : 0.0f;
  float s = e0 + e1 + e2;
  for (int off = 32; off; off >>= 1) s += __shfl_down(s, off);
  s = __shfl(s, 0);
  float* p = probs + (size_t)row * NCP;
  p[t] = (t == 0) ? 0.0f : (e0 / s);
  p[t + 64] = e1 / s;
  if (t + 128 < NC) p[t + 128] = e2 / s;
  if (t == 0) p[NC] = -1.0f;  // pad col never wins a scan
}

// ---------------- transpose boxes to [C][N][4] ----------------
__global__ __launch_bounds__(256) void transpose_kernel(
    const float* __restrict__ boxes, float* __restrict__ boxes_t) {
  int idx = blockIdx.x * 256 + threadIdx.x;  // idx = c*NB + n
  if (idx >= NC * NB) return;
  int c = idx >> 10;
  int n = idx & (NB - 1);
  float4 b = *(const float4*)(boxes + ((size_t)n * NC + c) * 4);
  *(float4*)(boxes_t + (size_t)idx * 4) = b;
}

// ---------------- precompute overlap bitmask: mask[cl][b] = 1024 bits ----------------
__global__ __launch_bounds__(256) void mask_kernel(
    const float* __restrict__ boxes_t, u64* __restrict__ mask) {
#pragma clang fp contract(off)
  int cl = blockIdx.x >> 4;          // 151 classes
  int bb = (blockIdx.x & 15) * 64;   // 16 b-groups of 64
  __shared__ float4 sbox[NB];
  __shared__ float sarea[NB];
  const float4* col = (const float4*)(boxes_t + (size_t)cl * NB * 4);
  for (int i = threadIdx.x; i < NB; i += 256) {
    float4 b = col[i];
    sbox[i] = b;
    sarea[i] = (b.z - b.x + 1.0f) * (b.w - b.y + 1.0f);
  }
  __syncthreads();
  int wv = threadIdx.x >> 6, lane = threadIdx.x & 63;
  for (int j = 0; j < 16; ++j) {
    int b = bb + wv * 16 + j;
    float4 B = sbox[b];
    float areaB = sarea[b];
    u64 myword = 0;
#pragma unroll
    for (int k = 0; k < 16; ++k) {
      int r = k * 64 + lane;
      float4 R = sbox[r];
      float ix = fminf(B.z, R.z) - fmaxf(B.x, R.x) + 1.0f;
      float iy = fminf(B.w, R.w) - fmaxf(B.y, R.y) + 1.0f;
      ix = fmaxf(ix, 0.0f);
      iy = fmaxf(iy, 0.0f);
      float inter = ix * iy;
      float uni = sarea[r] + areaB - inter;
      float iou = inter / uni;            // IEEE div — must match numpy exactly
      u64 bal = __ballot(iou >= 0.5f);
      if (lane == k) myword = bal;
    }
    if (lane < 16) mask[((size_t)cl * NB + b) * 16 + lane] = myword;
  }
}

// ---------------- greedy commit: ONE wave, batch-4 lazy-greedy ----------------
template <int CTRL, int ROWMASK>
__device__ __forceinline__ float dpp_max_step(float v) {
  int x = __float_as_int(v);
  int t = __builtin_amdgcn_update_dpp(x, x, CTRL, ROWMASK, 0xf, false);
  return fmaxf(v, __int_as_float(t));
}

// canonical gfx9 wave64 max reduce; result broadcast via readlane(63)
__device__ __forceinline__ float wave_max(float v) {
  v = dpp_max_step<0x111, 0xf>(v);  // row_shr:1
  v = dpp_max_step<0x112, 0xf>(v);  // row_shr:2
  v = dpp_max_step<0x114, 0xf>(v);  // row_shr:4
  v = dpp_max_step<0x118, 0xf>(v);  // row_shr:8
  v = dpp_max_step<0x142, 0xa>(v);  // row_bcast:15
  v = dpp_max_step<0x143, 0xc>(v);  // row_bcast:31
  return __int_as_float(__builtin_amdgcn_readlane(__float_as_int(v), 63));
}

// scan a read-only probs row with zeroed-class bitmask applied; strict >, first max.
__device__ __forceinline__ void rescan_row(const float* __restrict__ pp,
                                           u64 z0, u64 z1, u64 z2,
                                           float& mo, int& ao) {
  const float4* p4 = (const float4*)pp;
  float m = 0.0f; int a = 0;
#pragma unroll 2
  for (int q = 0; q < NCP / 4; ++q) {
    float4 v = p4[q];
    u64 z = q < 16 ? z0 : (q < 32 ? z1 : z2);
    unsigned bits = (unsigned)(z >> ((q & 15) * 4)) & 0xFu;
    int c0 = q * 4;
    float vx = (bits & 1u) ? 0.0f : v.x;
    float vy = (bits & 2u) ? 0.0f : v.y;
    float vz = (bits & 4u) ? 0.0f : v.z;
    float vw = (bits & 8u) ? 0.0f : v.w;
    if (vx > m) { m = vx; a = c0; }
    if (vy > m) { m = vy; a = c0 + 1; }
    if (vz > m) { m = vz; a = c0 + 2; }
    if (vw > m) { m = vw; a = c0 + 3; }
  }
  mo = m; ao = a;
}

// one sequential commit's state update (fully inlined; static indices after unroll)
__device__ __forceinline__ void apply_commit(
    int lane, int b, int cl, unsigned hits,
    float rm[16], int ra[16], int cm[16],
    u64 zb0[16], u64 zb1[16], u64 zb2[16],
    unsigned& committed, unsigned& need) {
  int blo = b & 15, bhi = b >> 4;
  int wi = cl >> 6;
  u64 bmm = 1ull << (cl & 63);
  u64 q0 = wi == 0 ? bmm : 0ull, q1 = wi == 1 ? bmm : 0ull, q2 = wi == 2 ? bmm : 0ull;
  bool meL = (lane == bhi);
#pragma unroll
  for (int r = 0; r < 16; ++r) {
    unsigned rb = 1u << r;
    bool hit = (hits & rb) != 0;
    if (r == blo) {              // scalar compare (blo uniform)
      if (meL) { committed |= rb; rm[r] = -1.0f; cm[r] = cl; hit = false; }
    }
    if (hit) {
      if (committed & rb) {
        // committed row: -1 everywhere except re-zeroed cols (0)
        if (rm[r] < 0.0f) { rm[r] = 0.0f; ra[r] = cl; }
        else if (cl < ra[r]) ra[r] = cl;
      } else {
        zb0[r] |= q0; zb1[r] |= q1; zb2[r] |= q2;
        if (ra[r] == cl) need |= rb;  // max may have dropped
      }
    }
  }
}

__global__ __launch_bounds__(64) void greedy_kernel(
    const float* __restrict__ probs, const u64* __restrict__ mask,
    float* __restrict__ out_preds) {
  int lane = threadIdx.x;
  float rm[16];
  int ra[16];
  int cm[16];
  u64 zb0[16], zb1[16], zb2[16];
  unsigned committed = 0;

  auto local_best = [&](unsigned selm, float& obv, int& obp) {
    float v = (selm & 1u) ? -2.0f : rm[0];
    int p = ra[0];
#pragma unroll
    for (int r = 1; r < 16; ++r) {
      float vr = (selm & (1u << r)) ? -2.0f : rm[r];
      bool t = vr > v;
      v = t ? vr : v;
      p = t ? ((r << 8) | ra[r]) : p;
    }
    obv = v; obp = p;
  };

  // ---- init: scan my 16 rows ----
#pragma unroll
  for (int r = 0; r < 16; ++r) {
    rescan_row(probs + (size_t)((lane << 4) | r) * NCP, 0, 0, 0, rm[r], ra[r]);
    cm[r] = 0; zb0[r] = 0; zb1[r] = 0; zb2[r] = 0;
  }

  int done = 0;
  while (done < NB) {
    // ================= selection: up to 4 candidates from frozen state =================
    unsigned sel = 0;
    float bv; int bp;
    local_best(0u, bv, bp);

    // pick 0 (always valid: uses fully-fresh state)
    float wm = wave_max(bv);
    u64 ba = __ballot(bv == wm);
    int wn = __ffsll(ba) - 1;                 // smallest lane = smallest row
    int pw = __builtin_amdgcn_readlane(bp, wn);
    int b0 = (wn << 4) | (pw >> 8);
    int ra0 = pw & 0xff;
    int cl0 = (wm < 0.0f) ? 0 : ra0;          // all-(-1) endgame: argmax -> class 0
    float val0 = wm;
    if (lane == wn) sel |= 1u << (pw >> 8);
    u64 word0 = mask[(((size_t)cl0 << 10) | (size_t)b0) * 16 + (lane >> 2)];

    int b1 = 0, cl1 = 0, ra1 = 0; float val1 = -3.0f; u64 word1 = 0;
    int b2 = 0, cl2 = 0, ra2 = 0; float val2 = -3.0f; u64 word2 = 0;
    int b3 = 0, cl3 = 0, ra3 = 0; float val3 = -3.0f; u64 word3 = 0;

    if (val0 > 0.0f) {
      if (lane == (b0 >> 4)) local_best(sel, bv, bp);
      wm = wave_max(bv);
      ba = __ballot(bv == wm); wn = __ffsll(ba) - 1;
      pw = __builtin_amdgcn_readlane(bp, wn);
      b1 = (wn << 4) | (pw >> 8); ra1 = pw & 0xff; cl1 = ra1; val1 = wm;
      if (lane == wn) sel |= 1u << (pw >> 8);
      word1 = mask[(((size_t)cl1 << 10) | (size_t)b1) * 16 + (lane >> 2)];

      if (val1 > 0.0f) {
        if (lane == (b1 >> 4)) local_best(sel, bv, bp);
        wm = wave_max(bv);
        ba = __ballot(bv == wm); wn = __ffsll(ba) - 1;
        pw = __builtin_amdgcn_readlane(bp, wn);
        b2 = (wn << 4) | (pw >> 8); ra2 = pw & 0xff; cl2 = ra2; val2 = wm;
        if (lane == wn) sel |= 1u << (pw >> 8);
        word2 = mask[(((size_t)cl2 << 10) | (size_t)b2) * 16 + (lane >> 2)];

        if (val2 > 0.0f) {
          if (lane == (b2 >> 4)) local_best(sel, bv, bp);
          wm = wave_max(bv);
          ba = __ballot(bv == wm); wn = __ffsll(ba) - 1;
          pw = __builtin_amdgcn_readlane(bp, wn);
          b3 = (wn << 4) | (pw >> 8); ra3 = pw & 0xff; cl3 = ra3; val3 = wm;
          if (lane == wn) sel |= 1u << (pw >> 8);
          word3 = mask[(((size_t)cl3 << 10) | (size_t)b3) * 16 + (lane >> 2)];
        }
      }
    }

    // ================= hits + validity (lazy-greedy abort) =================
    unsigned hits0 = (unsigned)(word0 >> ((lane & 3) << 4)) & 0xFFFFu;
    unsigned hits1 = (unsigned)(word1 >> ((lane & 3) << 4)) & 0xFFFFu;
    unsigned hits2 = (unsigned)(word2 >> ((lane & 3) << 4)) & 0xFFFFu;
    unsigned hits3 = (unsigned)(word3 >> ((lane & 3) << 4)) & 0xFFFFu;

    int m = 1;
    if (val1 > 0.0f) {
      unsigned h0 = (unsigned)__builtin_amdgcn_readlane((int)hits0, b1 >> 4);
      bool ok = !(((h0 >> (b1 & 15)) & 1u) && (cl0 == ra1));
      if (ok) {
        m = 2;
        if (val2 > 0.0f) {
          unsigned g0 = (unsigned)__builtin_amdgcn_readlane((int)hits0, b2 >> 4);
          unsigned g1 = (unsigned)__builtin_amdgcn_readlane((int)hits1, b2 >> 4);
          bool ok2 = !(((g0 >> (b2 & 15)) & 1u) && (cl0 == ra2)) &&
                     !(((g1 >> (b2 & 15)) & 1u) && (cl1 == ra2));
          if (ok2) {
            m = 3;
            if (val3 > 0.0f) {
              unsigned f0 = (unsigned)__builtin_amdgcn_readlane((int)hits0, b3 >> 4);
              unsigned f1 = (unsigned)__builtin_amdgcn_readlane((int)hits1, b3 >> 4);
              unsigned f2 = (unsigned)__builtin_amdgcn_readlane((int)hits2, b3 >> 4);
              bool ok3 = !(((f0 >> (b3 & 15)) & 1u) && (cl0 == ra3)) &&
                         !(((f1 >> (b3 & 15)) & 1u) && (cl1 == ra3)) &&
                         !(((f2 >> (b3 & 15)) & 1u) && (cl2 == ra3));
              if (ok3) m = 4;
            }
          }
        }
      }
    }
    if (m > NB - done) m = NB - done;
    done += m;

    // ================= apply the valid prefix sequentially =================
    unsigned need = 0;
    apply_commit(lane, b0, cl0, hits0, rm, ra, cm, zb0, zb1, zb2, committed, need);
    if (1 < m) apply_commit(lane, b1, cl1, hits1, rm, ra, cm, zb0, zb1, zb2, committed, need);
    if (2 < m) apply_commit(lane, b2, cl2, hits2, rm, ra, cm, zb0, zb1, zb2, committed, need);
    if (3 < m) apply_commit(lane, b3, cl3, hits3, rm, ra, cm, zb0, zb1, zb2, committed, need);

    // ================= one merged rescan phase per batch =================
    if (__ballot(need != 0)) {
#pragma unroll
      for (int r = 0; r < 16; ++r) {
        if (need & (1u << r))
          rescan_row(probs + (size_t)((lane << 4) | r) * NCP,
                     zb0[r], zb1[r], zb2[r], rm[r], ra[r]);
      }
    }
  }

  // ---- write commits ----
#pragma unroll
  for (int r = 0; r < 16; ++r)
    out_preds[(lane << 4) | r] = (float)cm[r];
}

// ---------------- host ----------------
extern "C" void kernel_launch(void* const* d_in, const int* in_sizes, int n_in,
                              void* d_out, int out_size, void* d_ws, size_t ws_size,
                              hipStream_t stream) {
  const float* obj_fmap = (const float*)d_in[0];  // [NB, DF]
  const float* W_out    = (const float*)d_in[1];  // [DF, NC]
  const float* b_out    = (const float*)d_in[2];  // [NC]
  const float* boxes    = (const float*)d_in[3];  // [NB, NC, 4]

  float* out_dists = (float*)d_out;            // NB*NC
  float* out_preds = (float*)d_out + NB * NC;  // NB (as float)

  float* probs   = (float*)d_ws;                        // NB*NCP floats
  float* boxes_t = probs + (size_t)NB * NCP;            // NC*NB*4 floats
  u64*   mask    = (u64*)(boxes_t + (size_t)NC * NB * 4);  // NC*NB*16 u64 (19.8 MB)

  gemm_kernel<<<NB / 4, 192, 0, stream>>>(obj_fmap, W_out, b_out, out_dists);
  softmax_kernel<<<NB, 64, 0, stream>>>(out_dists, probs);
  transpose_kernel<<<(NC * NB + 255) / 256, 256, 0, stream>>>(boxes, boxes_t);
  mask_kernel<<<NC * 16, 256, 0, stream>>>(boxes_t, mask);
  greedy_kernel<<<1, 64, 0, stream>>>(probs, mask, out_preds);
}

// Round 8
// 2182.786 us; speedup vs baseline: 1.3486x; 1.0147x over previous
//
#include <hip/hip_runtime.h>

#define NB 1024   // boxes
#define NC 151    // classes
#define NCP 152   // padded probs row stride (16B-aligned)
#define DF 4096   // feature dim
typedef unsigned long long u64;

// ---------------- GEMM: dists = fmap @ W + b (fp32 in, f64 accum) ----------------
__global__ __launch_bounds__(192) void gemm_kernel(
    const float* __restrict__ fmap, const float* __restrict__ W,
    const float* __restrict__ bias, float* __restrict__ dists) {
  __shared__ float sf[4 * DF];  // 64 KiB
  int r0 = blockIdx.x * 4;
  const float4* src = (const float4*)(fmap + (size_t)r0 * DF);
  for (int i = threadIdx.x; i < 4 * (DF / 4); i += 192) {
    int r = i >> 10;       // row 0..3
    int q = i & 1023;      // float4 index within row
    float4 v = src[i];
    sf[(4 * q + 0) * 4 + r] = v.x;
    sf[(4 * q + 1) * 4 + r] = v.y;
    sf[(4 * q + 2) * 4 + r] = v.z;
    sf[(4 * q + 3) * 4 + r] = v.w;
  }
  __syncthreads();
  int c = threadIdx.x;
  if (c < NC) {
    double a0 = 0.0, a1 = 0.0, a2 = 0.0, a3 = 0.0;
    const float* w = W + c;
    const float4* sf4 = (const float4*)sf;
#pragma unroll 8
    for (int d = 0; d < DF; ++d) {
      float4 f = sf4[d];                       // broadcast across wave
      double wv = (double)w[(size_t)d * NC];   // coalesced across threads
      a0 += (double)f.x * wv;
      a1 += (double)f.y * wv;
      a2 += (double)f.z * wv;
      a3 += (double)f.w * wv;
    }
    float b = bias[c];
    dists[(size_t)(r0 + 0) * NC + c] = (float)a0 + b;
    dists[(size_t)(r0 + 1) * NC + c] = (float)a1 + b;
    dists[(size_t)(r0 + 2) * NC + c] = (float)a2 + b;
    dists[(size_t)(r0 + 3) * NC + c] = (float)a3 + b;
  }
}

// ---------------- softmax rows into padded probs, zero background col ----------------
__global__ __launch_bounds__(64) void softmax_kernel(
    const float* __restrict__ dists, float* __restrict__ probs) {
  int row = blockIdx.x;
  int t = threadIdx.x;
  const float* x = dists + (size_t)row * NC;
  float v0 = x[t];
  float v1 = x[t + 64];
  float v2 = (t + 128 < NC) ? x[t + 128] : -3.0e38f;
  float m = fmaxf(fmaxf(v0, v1), v2);
  for (int off = 32; off; off >>= 1) m = fmaxf(m, __shfl_down(m, off));
  m = __shfl(m, 0);
  float e0 = expf(v0 - m), e1 = expf(v1 - m);
  float e2 = (t + 128 < NC) ? expf(v2 - m) : 0.0f;
  float s = e0 + e1 + e2;
  for (int off = 32; off; off >>= 1) s += __shfl_down(s, off);
  s = __shfl(s, 0);
  float* p = probs + (size_t)row * NCP;
  p[t] = (t == 0) ? 0.0f : (e0 / s);
  p[t + 64] = e1 / s;
  if (t + 128 < NC) p[t + 128] = e2 / s;
  if (t == 0) p[NC] = -1.0f;  // pad col never wins a scan
}

// ---------------- transpose boxes to [C][N][4] ----------------
__global__ __launch_bounds__(256) void transpose_kernel(
    const float* __restrict__ boxes, float* __restrict__ boxes_t) {
  int idx = blockIdx.x * 256 + threadIdx.x;  // idx = c*NB + n
  if (idx >= NC * NB) return;
  int c = idx >> 10;
  int n = idx & (NB - 1);
  float4 b = *(const float4*)(boxes + ((size_t)n * NC + c) * 4);
  *(float4*)(boxes_t + (size_t)idx * 4) = b;
}

// ---------------- precompute overlap bitmask: mask[cl][b] = 1024 bits ----------------
__global__ __launch_bounds__(256) void mask_kernel(
    const float* __restrict__ boxes_t, u64* __restrict__ mask) {
#pragma clang fp contract(off)
  int cl = blockIdx.x >> 4;          // 151 classes
  int bb = (blockIdx.x & 15) * 64;   // 16 b-groups of 64
  __shared__ float4 sbox[NB];
  __shared__ float sarea[NB];
  const float4* col = (const float4*)(boxes_t + (size_t)cl * NB * 4);
  for (int i = threadIdx.x; i < NB; i += 256) {
    float4 b = col[i];
    sbox[i] = b;
    sarea[i] = (b.z - b.x + 1.0f) * (b.w - b.y + 1.0f);
  }
  __syncthreads();
  int wv = threadIdx.x >> 6, lane = threadIdx.x & 63;
  for (int j = 0; j < 16; ++j) {
    int b = bb + wv * 16 + j;
    float4 B = sbox[b];
    float areaB = sarea[b];
    u64 myword = 0;
#pragma unroll
    for (int k = 0; k < 16; ++k) {
      int r = k * 64 + lane;
      float4 R = sbox[r];
      float ix = fminf(B.z, R.z) - fmaxf(B.x, R.x) + 1.0f;
      float iy = fminf(B.w, R.w) - fmaxf(B.y, R.y) + 1.0f;
      ix = fmaxf(ix, 0.0f);
      iy = fmaxf(iy, 0.0f);
      float inter = ix * iy;
      float uni = sarea[r] + areaB - inter;
      float iou = inter / uni;            // IEEE div — must match numpy exactly
      u64 bal = __ballot(iou >= 0.5f);
      if (lane == k) myword = bal;
    }
    if (lane < 16) mask[((size_t)cl * NB + b) * 16 + lane] = myword;
  }
}

// ---------------- greedy commit: ONE wave, batch-4 lazy-greedy, full-VGPR ----------------
template <int CTRL, int ROWMASK>
__device__ __forceinline__ float dpp_max_step(float v) {
  int x = __float_as_int(v);
  int t = __builtin_amdgcn_update_dpp(x, x, CTRL, ROWMASK, 0xf, false);
  return fmaxf(v, __int_as_float(t));
}

// canonical gfx9 wave64 max reduce; result broadcast via readlane(63)
__device__ __forceinline__ float wave_max(float v) {
  v = dpp_max_step<0x111, 0xf>(v);  // row_shr:1
  v = dpp_max_step<0x112, 0xf>(v);  // row_shr:2
  v = dpp_max_step<0x114, 0xf>(v);  // row_shr:4
  v = dpp_max_step<0x118, 0xf>(v);  // row_shr:8
  v = dpp_max_step<0x142, 0xa>(v);  // row_bcast:15
  v = dpp_max_step<0x143, 0xc>(v);  // row_bcast:31
  return __int_as_float(__builtin_amdgcn_readlane(__float_as_int(v), 63));
}

// scan a read-only probs row with zeroed-class bitmask applied; strict >, first max.
__device__ __forceinline__ void rescan_row(const float* __restrict__ pp,
                                           u64 z0, u64 z1, u64 z2,
                                           float& mo, int& ao) {
  const float4* p4 = (const float4*)pp;
  float m = 0.0f; int a = 0;
#pragma unroll 2
  for (int q = 0; q < NCP / 4; ++q) {
    float4 v = p4[q];
    u64 z = q < 16 ? z0 : (q < 32 ? z1 : z2);
    unsigned bits = (unsigned)(z >> ((q & 15) * 4)) & 0xFu;
    int c0 = q * 4;
    float vx = (bits & 1u) ? 0.0f : v.x;
    float vy = (bits & 2u) ? 0.0f : v.y;
    float vz = (bits & 4u) ? 0.0f : v.z;
    float vw = (bits & 8u) ? 0.0f : v.w;
    if (vx > m) { m = vx; a = c0; }
    if (vy > m) { m = vy; a = c0 + 1; }
    if (vz > m) { m = vz; a = c0 + 2; }
    if (vw > m) { m = vw; a = c0 + 3; }
  }
  mo = m; ao = a;
}

// one sequential commit's state update (fully inlined; static indices after unroll)
__device__ __forceinline__ void apply_commit(
    int lane, int b, int cl, unsigned hits,
    float rm[16], int ra[16], int cm[16],
    u64 zb0[16], u64 zb1[16], u64 zb2[16],
    unsigned& committed, unsigned& need) {
  int blo = b & 15, bhi = b >> 4;
  int wi = cl >> 6;
  u64 bmm = 1ull << (cl & 63);
  u64 q0 = wi == 0 ? bmm : 0ull, q1 = wi == 1 ? bmm : 0ull, q2 = wi == 2 ? bmm : 0ull;
  bool meL = (lane == bhi);
#pragma unroll
  for (int r = 0; r < 16; ++r) {
    unsigned rb = 1u << r;
    bool hit = (hits & rb) != 0;
    if (r == blo) {              // scalar compare (blo uniform)
      if (meL) { committed |= rb; rm[r] = -1.0f; cm[r] = cl; hit = false; }
    }
    if (hit) {
      if (committed & rb) {
        // committed row: -1 everywhere except re-zeroed cols (0)
        if (rm[r] < 0.0f) { rm[r] = 0.0f; ra[r] = cl; }
        else if (cl < ra[r]) ra[r] = cl;
      } else {
        zb0[r] |= q0; zb1[r] |= q1; zb2[r] |= q2;
        if (ra[r] == cl) need |= rb;  // max may have dropped
      }
    }
  }
}

__global__ __launch_bounds__(64, 1) void greedy_kernel(
    const float* __restrict__ probs, const u64* __restrict__ mask,
    float* __restrict__ out_preds) {
  int lane = threadIdx.x;
  float rm[16];
  int ra[16];
  int cm[16];
  u64 zb0[16], zb1[16], zb2[16];
  unsigned committed = 0;

  // tree-structured local argmax (depth 4); selm-excluded rows -> -2; ties -> smaller row
  auto local_best = [&](unsigned selm, float& obv, int& obp) {
    float tv[8]; int tp[8];
#pragma unroll
    for (int i = 0; i < 8; ++i) {
      int r0 = 2 * i, r1 = 2 * i + 1;
      float a = (selm & (1u << r0)) ? -2.0f : rm[r0];
      float b = (selm & (1u << r1)) ? -2.0f : rm[r1];
      int pa = (r0 << 8) | ra[r0];
      int pb = (r1 << 8) | ra[r1];
      bool t = b > a;
      tv[i] = t ? b : a; tp[i] = t ? pb : pa;
    }
#pragma unroll
    for (int i = 0; i < 4; ++i) {
      bool t = tv[2 * i + 1] > tv[2 * i];
      tv[i] = t ? tv[2 * i + 1] : tv[2 * i];
      tp[i] = t ? tp[2 * i + 1] : tp[2 * i];
    }
#pragma unroll
    for (int i = 0; i < 2; ++i) {
      bool t = tv[2 * i + 1] > tv[2 * i];
      tv[i] = t ? tv[2 * i + 1] : tv[2 * i];
      tp[i] = t ? tp[2 * i + 1] : tp[2 * i];
    }
    bool t = tv[1] > tv[0];
    obv = t ? tv[1] : tv[0];
    obp = t ? tp[1] : tp[0];
  };

  // ---- init: scan my 16 rows ----
#pragma unroll
  for (int r = 0; r < 16; ++r) {
    rescan_row(probs + (size_t)((lane << 4) | r) * NCP, 0, 0, 0, rm[r], ra[r]);
    cm[r] = 0; zb0[r] = 0; zb1[r] = 0; zb2[r] = 0;
  }

  int done = 0;
  while (done < NB) {
    // ================= selection: up to 4 candidates from frozen state =================
    unsigned sel = 0;
    float bv; int bp;
    local_best(0u, bv, bp);

    // pick 0 (always valid: uses fully-fresh state)
    float wm = wave_max(bv);
    u64 ba = __ballot(bv == wm);
    int wn = __ffsll(ba) - 1;                 // smallest lane = smallest row
    int pw = __builtin_amdgcn_readlane(bp, wn);
    int b0 = (wn << 4) | (pw >> 8);
    int ra0 = pw & 0xff;
    int cl0 = (wm < 0.0f) ? 0 : ra0;          // all-(-1) endgame: argmax -> class 0
    float val0 = wm;
    if (lane == wn) sel |= 1u << (pw >> 8);
    u64 word0 = mask[(((size_t)cl0 << 10) | (size_t)b0) * 16 + (lane >> 2)];

    int b1 = 0, cl1 = 0, ra1 = 0; float val1 = -3.0f; u64 word1 = 0;
    int b2 = 0, cl2 = 0, ra2 = 0; float val2 = -3.0f; u64 word2 = 0;
    int b3 = 0, cl3 = 0, ra3 = 0; float val3 = -3.0f; u64 word3 = 0;

    if (val0 > 0.0f) {
      if (lane == (b0 >> 4)) local_best(sel, bv, bp);
      wm = wave_max(bv);
      ba = __ballot(bv == wm); wn = __ffsll(ba) - 1;
      pw = __builtin_amdgcn_readlane(bp, wn);
      b1 = (wn << 4) | (pw >> 8); ra1 = pw & 0xff; cl1 = ra1; val1 = wm;
      if (lane == wn) sel |= 1u << (pw >> 8);
      word1 = mask[(((size_t)cl1 << 10) | (size_t)b1) * 16 + (lane >> 2)];

      if (val1 > 0.0f) {
        if (lane == (b1 >> 4)) local_best(sel, bv, bp);
        wm = wave_max(bv);
        ba = __ballot(bv == wm); wn = __ffsll(ba) - 1;
        pw = __builtin_amdgcn_readlane(bp, wn);
        b2 = (wn << 4) | (pw >> 8); ra2 = pw & 0xff; cl2 = ra2; val2 = wm;
        if (lane == wn) sel |= 1u << (pw >> 8);
        word2 = mask[(((size_t)cl2 << 10) | (size_t)b2) * 16 + (lane >> 2)];

        if (val2 > 0.0f) {
          if (lane == (b2 >> 4)) local_best(sel, bv, bp);
          wm = wave_max(bv);
          ba = __ballot(bv == wm); wn = __ffsll(ba) - 1;
          pw = __builtin_amdgcn_readlane(bp, wn);
          b3 = (wn << 4) | (pw >> 8); ra3 = pw & 0xff; cl3 = ra3; val3 = wm;
          if (lane == wn) sel |= 1u << (pw >> 8);
          word3 = mask[(((size_t)cl3 << 10) | (size_t)b3) * 16 + (lane >> 2)];
        }
      }
    }

    // ================= hits + validity (lazy-greedy abort) =================
    unsigned hits0 = (unsigned)(word0 >> ((lane & 3) << 4)) & 0xFFFFu;
    unsigned hits1 = (unsigned)(word1 >> ((lane & 3) << 4)) & 0xFFFFu;
    unsigned hits2 = (unsigned)(word2 >> ((lane & 3) << 4)) & 0xFFFFu;
    unsigned hits3 = (unsigned)(word3 >> ((lane & 3) << 4)) & 0xFFFFu;

    int m = 1;
    if (val1 > 0.0f) {
      unsigned h0 = (unsigned)__builtin_amdgcn_readlane((int)hits0, b1 >> 4);
      bool ok = !(((h0 >> (b1 & 15)) & 1u) && (cl0 == ra1));
      if (ok) {
        m = 2;
        if (val2 > 0.0f) {
          unsigned g0 = (unsigned)__builtin_amdgcn_readlane((int)hits0, b2 >> 4);
          unsigned g1 = (unsigned)__builtin_amdgcn_readlane((int)hits1, b2 >> 4);
          bool ok2 = !(((g0 >> (b2 & 15)) & 1u) && (cl0 == ra2)) &&
                     !(((g1 >> (b2 & 15)) & 1u) && (cl1 == ra2));
          if (ok2) {
            m = 3;
            if (val3 > 0.0f) {
              unsigned f0 = (unsigned)__builtin_amdgcn_readlane((int)hits0, b3 >> 4);
              unsigned f1 = (unsigned)__builtin_amdgcn_readlane((int)hits1, b3 >> 4);
              unsigned f2 = (unsigned)__builtin_amdgcn_readlane((int)hits2, b3 >> 4);
              bool ok3 = !(((f0 >> (b3 & 15)) & 1u) && (cl0 == ra3)) &&
                         !(((f1 >> (b3 & 15)) & 1u) && (cl1 == ra3)) &&
                         !(((f2 >> (b3 & 15)) & 1u) && (cl2 == ra3));
              if (ok3) m = 4;
            }
          }
        }
      }
    }
    if (m > NB - done) m = NB - done;
    done += m;

    // ================= apply the valid prefix sequentially =================
    unsigned need = 0;
    apply_commit(lane, b0, cl0, hits0, rm, ra, cm, zb0, zb1, zb2, committed, need);
    if (1 < m) apply_commit(lane, b1, cl1, hits1, rm, ra, cm, zb0, zb1, zb2, committed, need);
    if (2 < m) apply_commit(lane, b2, cl2, hits2, rm, ra, cm, zb0, zb1, zb2, committed, need);
    if (3 < m) apply_commit(lane, b3, cl3, hits3, rm, ra, cm, zb0, zb1, zb2, committed, need);

    // ================= one merged rescan phase per batch =================
    if (__ballot(need != 0)) {
#pragma unroll
      for (int r = 0; r < 16; ++r) {
        if (need & (1u << r))
          rescan_row(probs + (size_t)((lane << 4) | r) * NCP,
                     zb0[r], zb1[r], zb2[r], rm[r], ra[r]);
      }
    }
  }

  // ---- write commits ----
#pragma unroll
  for (int r = 0; r < 16; ++r)
    out_preds[(lane << 4) | r] = (float)cm[r];
}

// ---------------- host ----------------
extern "C" void kernel_launch(void* const* d_in, const int* in_sizes, int n_in,
                              void* d_out, int out_size, void* d_ws, size_t ws_size,
                              hipStream_t stream) {
  const float* obj_fmap = (const float*)d_in[0];  // [NB, DF]
  const float* W_out    = (const float*)d_in[1];  // [DF, NC]
  const float* b_out    = (const float*)d_in[2];  // [NC]
  const float* boxes    = (const float*)d_in[3];  // [NB, NC, 4]

  float* out_dists = (float*)d_out;            // NB*NC
  float* out_preds = (float*)d_out + NB * NC;  // NB (as float)

  float* probs   = (float*)d_ws;                        // NB*NCP floats
  float* boxes_t = probs + (size_t)NB * NCP;            // NC*NB*4 floats
  u64*   mask    = (u64*)(boxes_t + (size_t)NC * NB * 4);  // NC*NB*16 u64 (19.8 MB)

  gemm_kernel<<<NB / 4, 192, 0, stream>>>(obj_fmap, W_out, b_out, out_dists);
  softmax_kernel<<<NB, 64, 0, stream>>>(out_dists, probs);
  transpose_kernel<<<(NC * NB + 255) / 256, 256, 0, stream>>>(boxes, boxes_t);
  mask_kernel<<<NC * 16, 256, 0, stream>>>(boxes_t, mask);
  greedy_kernel<<<1, 64, 0, stream>>>(probs, mask, out_preds);
}

// Round 9
// 2033.342 us; speedup vs baseline: 1.4477x; 1.0735x over previous
//
#include <hip/hip_runtime.h>

#define NB 1024   // boxes
#define NC 151    // classes
#define NCP 152   // padded probs row stride (16B-aligned)
#define DF 4096   // feature dim
typedef unsigned long long u64;

// ---------------- GEMM: dists = fmap @ W + b (fp32 in, f64 accum) ----------------
__global__ __launch_bounds__(192) void gemm_kernel(
    const float* __restrict__ fmap, const float* __restrict__ W,
    const float* __restrict__ bias, float* __restrict__ dists) {
  __shared__ float sf[4 * DF];  // 64 KiB
  int r0 = blockIdx.x * 4;
  const float4* src = (const float4*)(fmap + (size_t)r0 * DF);
  for (int i = threadIdx.x; i < 4 * (DF / 4); i += 192) {
    int r = i >> 10;       // row 0..3
    int q = i & 1023;      // float4 index within row
    float4 v = src[i];
    sf[(4 * q + 0) * 4 + r] = v.x;
    sf[(4 * q + 1) * 4 + r] = v.y;
    sf[(4 * q + 2) * 4 + r] = v.z;
    sf[(4 * q + 3) * 4 + r] = v.w;
  }
  __syncthreads();
  int c = threadIdx.x;
  if (c < NC) {
    double a0 = 0.0, a1 = 0.0, a2 = 0.0, a3 = 0.0;
    const float* w = W + c;
    const float4* sf4 = (const float4*)sf;
#pragma unroll 8
    for (int d = 0; d < DF; ++d) {
      float4 f = sf4[d];                       // broadcast across wave
      double wv = (double)w[(size_t)d * NC];   // coalesced across threads
      a0 += (double)f.x * wv;
      a1 += (double)f.y * wv;
      a2 += (double)f.z * wv;
      a3 += (double)f.w * wv;
    }
    float b = bias[c];
    dists[(size_t)(r0 + 0) * NC + c] = (float)a0 + b;
    dists[(size_t)(r0 + 1) * NC + c] = (float)a1 + b;
    dists[(size_t)(r0 + 2) * NC + c] = (float)a2 + b;
    dists[(size_t)(r0 + 3) * NC + c] = (float)a3 + b;
  }
}

// ---------------- softmax rows into padded probs, zero background col ----------------
__global__ __launch_bounds__(64) void softmax_kernel(
    const float* __restrict__ dists, float* __restrict__ probs) {
  int row = blockIdx.x;
  int t = threadIdx.x;
  const float* x = dists + (size_t)row * NC;
  float v0 = x[t];
  float v1 = x[t + 64];
  float v2 = (t + 128 < NC) ? x[t + 128] : -3.0e38f;
  float m = fmaxf(fmaxf(v0, v1), v2);
  for (int off = 32; off; off >>= 1) m = fmaxf(m, __shfl_down(m, off));
  m = __shfl(m, 0);
  float e0 = expf(v0 - m), e1 = expf(v1 - m);
  float e2 = (t + 128 < NC) ? expf(v2 - m) : 0.0f;
  float s = e0 + e1 + e2;
  for (int off = 32; off; off >>= 1) s += __shfl_down(s, off);
  s = __shfl(s, 0);
  float* p = probs + (size_t)row * NCP;
  p[t] = (t == 0) ? 0.0f : (e0 / s);
  p[t + 64] = e1 / s;
  if (t + 128 < NC) p[t + 128] = e2 / s;
  if (t == 0) p[NC] = -1.0f;  // pad col never wins a scan
}

// ---------------- transpose boxes to [C][N][4] ----------------
__global__ __launch_bounds__(256) void transpose_kernel(
    const float* __restrict__ boxes, float* __restrict__ boxes_t) {
  int idx = blockIdx.x * 256 + threadIdx.x;  // idx = c*NB + n
  if (idx >= NC * NB) return;
  int c = idx >> 10;
  int n = idx & (NB - 1);
  float4 b = *(const float4*)(boxes + ((size_t)n * NC + c) * 4);
  *(float4*)(boxes_t + (size_t)idx * 4) = b;
}

// ---------------- precompute overlap bitmask: mask[cl][b] = 1024 bits ----------------
__global__ __launch_bounds__(256) void mask_kernel(
    const float* __restrict__ boxes_t, u64* __restrict__ mask) {
#pragma clang fp contract(off)
  int cl = blockIdx.x >> 4;          // 151 classes
  int bb = (blockIdx.x & 15) * 64;   // 16 b-groups of 64
  __shared__ float4 sbox[NB];
  __shared__ float sarea[NB];
  const float4* col = (const float4*)(boxes_t + (size_t)cl * NB * 4);
  for (int i = threadIdx.x; i < NB; i += 256) {
    float4 b = col[i];
    sbox[i] = b;
    sarea[i] = (b.z - b.x + 1.0f) * (b.w - b.y + 1.0f);
  }
  __syncthreads();
  int wv = threadIdx.x >> 6, lane = threadIdx.x & 63;
  for (int j = 0; j < 16; ++j) {
    int b = bb + wv * 16 + j;
    float4 B = sbox[b];
    float areaB = sarea[b];
    u64 myword = 0;
#pragma unroll
    for (int k = 0; k < 16; ++k) {
      int r = k * 64 + lane;
      float4 R = sbox[r];
      float ix = fminf(B.z, R.z) - fmaxf(B.x, R.x) + 1.0f;
      float iy = fminf(B.w, R.w) - fmaxf(B.y, R.y) + 1.0f;
      ix = fmaxf(ix, 0.0f);
      iy = fmaxf(iy, 0.0f);
      float inter = ix * iy;
      float uni = sarea[r] + areaB - inter;
      float iou = inter / uni;            // IEEE div — must match numpy exactly
      u64 bal = __ballot(iou >= 0.5f);
      if (lane == k) myword = bal;
    }
    if (lane < 16) mask[((size_t)cl * NB + b) * 16 + lane] = myword;
  }
}

// ---------------- greedy commit: ONE wave, LDS-prefetched argmax columns ----------------
template <int CTRL, int ROWMASK>
__device__ __forceinline__ float dpp_max_step(float v) {
  int x = __float_as_int(v);
  int t = __builtin_amdgcn_update_dpp(x, x, CTRL, ROWMASK, 0xf, false);
  return fmaxf(v, __int_as_float(t));
}

// canonical gfx9 wave64 max reduce; result broadcast via readlane(63)
__device__ __forceinline__ float wave_max(float v) {
  v = dpp_max_step<0x111, 0xf>(v);  // row_shr:1
  v = dpp_max_step<0x112, 0xf>(v);  // row_shr:2
  v = dpp_max_step<0x114, 0xf>(v);  // row_shr:4
  v = dpp_max_step<0x118, 0xf>(v);  // row_shr:8
  v = dpp_max_step<0x142, 0xa>(v);  // row_bcast:15
  v = dpp_max_step<0x143, 0xc>(v);  // row_bcast:31
  return __int_as_float(__builtin_amdgcn_readlane(__float_as_int(v), 63));
}

// scan a read-only probs row with zeroed-class bitmask applied; strict >, first max.
__device__ __forceinline__ void rescan_row(const float* __restrict__ pp,
                                           u64 z0, u64 z1, u64 z2,
                                           float& mo, int& ao) {
  const float4* p4 = (const float4*)pp;
  float m = 0.0f; int a = 0;
#pragma unroll 2
  for (int q = 0; q < NCP / 4; ++q) {
    float4 v = p4[q];
    u64 z = q < 16 ? z0 : (q < 32 ? z1 : z2);
    unsigned bits = (unsigned)(z >> ((q & 15) * 4)) & 0xFu;
    int c0 = q * 4;
    float vx = (bits & 1u) ? 0.0f : v.x;
    float vy = (bits & 2u) ? 0.0f : v.y;
    float vz = (bits & 4u) ? 0.0f : v.z;
    float vw = (bits & 8u) ? 0.0f : v.w;
    if (vx > m) { m = vx; a = c0; }
    if (vy > m) { m = vy; a = c0 + 1; }
    if (vz > m) { m = vz; a = c0 + 2; }
    if (vw > m) { m = vw; a = c0 + 3; }
  }
  mo = m; ao = a;
}

__global__ __launch_bounds__(64, 1) void greedy_kernel(
    const float* __restrict__ probs, const u64* __restrict__ mask,
    float* __restrict__ out_preds) {
  // 132 KB LDS: prefetched mask column (b, ra0[b]) per box + its class tag
  __shared__ u64 smask[NB * 16];      // 128 KB
  __shared__ unsigned pcls[NB];       // 4 KB

  int lane = threadIdx.x;
  float rm[16];
  int ra[16];
  int cm[16];
  u64 zb0[16], zb1[16], zb2[16];  // zeroed-class bits: word cl>>6, bit cl&63
  unsigned committed = 0;

  // ---- init: scan my 16 rows; publish initial argmax class ----
#pragma unroll
  for (int r = 0; r < 16; ++r) {
    rescan_row(probs + (size_t)((lane << 4) | r) * NCP, 0, 0, 0, rm[r], ra[r]);
    cm[r] = 0; zb0[r] = 0; zb1[r] = 0; zb2[r] = 0;
    pcls[(lane << 4) | r] = (unsigned)ra[r];
  }
  __syncthreads();

  // ---- prefetch 1024 columns (b, ra0[b]) into LDS: 4 cols/pass, 16 lanes/col ----
#pragma unroll 4
  for (int j = 0; j < NB; j += 4) {
    int col = j + (lane >> 4);
    int w = lane & 15;
    unsigned pc = pcls[col];
    smask[(col << 4) | w] = mask[(((size_t)pc << 10) | (size_t)col) * 16 + w];
  }
  __syncthreads();

  for (int it = 0; it < NB; ++it) {
    // ---- local argmax over my 16 rows (strict > ascending => smallest row on tie) ----
    float bv = rm[0];
    int bp = ra[0];  // packed (r<<8)|ra
#pragma unroll
    for (int r = 1; r < 16; ++r) {
      int p = (r << 8) | ra[r];
      bool t = rm[r] > bv;
      bv = t ? rm[r] : bv;
      bp = t ? p : bp;
    }

    // ---- wave winner ----
    float wmax = wave_max(bv);
    u64 ball = __ballot(bv == wmax);
    int winner = __ffsll(ball) - 1;        // smallest lane = smallest row
    int pw = __builtin_amdgcn_readlane(bp, winner);
    int b = (winner << 4) | (pw >> 8);
    int cl = pw & 0xff;

    // ---- mask word: LDS if class matches the prefetched column, else global ----
    u64 word;
    unsigned pc = pcls[b];                 // uniform-address broadcast read
    if ((unsigned)cl == pc) {
      word = smask[((unsigned)b << 4) | (unsigned)(lane >> 2)];
    } else {
      word = mask[(((size_t)cl << 10) | (size_t)b) * 16 + (lane >> 2)];
    }

    // per-word bit of class cl (wave-uniform), branch-free — overlaps read wait
    int wi = cl >> 6;
    u64 bm = 1ull << (cl & 63);
    u64 m0 = (wi == 0) ? bm : 0, m1 = (wi == 1) ? bm : 0, m2 = (wi == 2) ? bm : 0;

    unsigned hits = (unsigned)(word >> ((lane & 3) << 4)) & 0xFFFFu;

    // ---- update my rows ----
    unsigned need = 0;
#pragma unroll
    for (int r = 0; r < 16; ++r) {
      int grow = (lane << 4) | r;
      unsigned rb = 1u << r;
      if (grow == b) {
        committed |= rb;
        rm[r] = -1.0f;       // row becomes all -1 (wipes prior re-zeros)
        cm[r] = cl;          // commit (or re-commit)
      } else if (hits & rb) {
        if (committed & rb) {
          // committed row: -1 everywhere except re-zeroed cols (0)
          if (rm[r] < 0.0f) { rm[r] = 0.0f; ra[r] = cl; }
          else if (cl < ra[r]) ra[r] = cl;
        } else {
          zb0[r] |= m0; zb1[r] |= m1; zb2[r] |= m2;
          if (ra[r] == cl) need |= rb;  // max may have dropped
        }
      }
    }
    if (__ballot(need != 0)) {  // uniform skip when no lane rescans
#pragma unroll
      for (int r = 0; r < 16; ++r) {
        if (need & (1u << r))
          rescan_row(probs + (size_t)((lane << 4) | r) * NCP,
                     zb0[r], zb1[r], zb2[r], rm[r], ra[r]);
      }
    }
  }

  // ---- write commits ----
#pragma unroll
  for (int r = 0; r < 16; ++r)
    out_preds[(lane << 4) | r] = (float)cm[r];
}

// ---------------- host ----------------
extern "C" void kernel_launch(void* const* d_in, const int* in_sizes, int n_in,
                              void* d_out, int out_size, void* d_ws, size_t ws_size,
                              hipStream_t stream) {
  const float* obj_fmap = (const float*)d_in[0];  // [NB, DF]
  const float* W_out    = (const float*)d_in[1];  // [DF, NC]
  const float* b_out    = (const float*)d_in[2];  // [NC]
  const float* boxes    = (const float*)d_in[3];  // [NB, NC, 4]

  float* out_dists = (float*)d_out;            // NB*NC
  float* out_preds = (float*)d_out + NB * NC;  // NB (as float)

  float* probs   = (float*)d_ws;                        // NB*NCP floats
  float* boxes_t = probs + (size_t)NB * NCP;            // NC*NB*4 floats
  u64*   mask    = (u64*)(boxes_t + (size_t)NC * NB * 4);  // NC*NB*16 u64 (19.8 MB)

  gemm_kernel<<<NB / 4, 192, 0, stream>>>(obj_fmap, W_out, b_out, out_dists);
  softmax_kernel<<<NB, 64, 0, stream>>>(out_dists, probs);
  transpose_kernel<<<(NC * NB + 255) / 256, 256, 0, stream>>>(boxes, boxes_t);
  mask_kernel<<<NC * 16, 256, 0, stream>>>(boxes_t, mask);
  greedy_kernel<<<1, 64, 0, stream>>>(probs, mask, out_preds);
}